// Round 3
// baseline (1534.314 us; speedup 1.0000x reference)
//
#include <hip/hip_runtime.h>
#include <hip/hip_bf16.h>

// SliceAttention on MI355X — round 6: fused 3-term K-tile GEMM.
// Round-5 measured: bank conflicts 0 (swizzle verified), MfmaUtil 46% —
// LDS-read traffic (384 B/MFMA over 3 segment passes) serializes against
// MFMA under barrier alignment. This round stages all 4 arrays (Ah,Al,Bh,Bl)
// per BK=32 K-tile (2 x 64KB buffers) and runs the 3 terms with register
// reuse: ah+bh -> AhBh; +bl (ah reused) -> AhBl; +al (bh reused) -> AlBh.
// 256 B/MFMA (-33% LDS reads), 4 instead of 6 global array passes.

#define NTOK 32768   // B*N
#define HH   1024
#define NHD  16
#define DD   64

typedef short short8 __attribute__((ext_vector_type(8)));
typedef float f32x4 __attribute__((ext_vector_type(4)));

#define AS1 __attribute__((address_space(1)))
#define AS3 __attribute__((address_space(3)))

__device__ __forceinline__ void glds16(const void* g, void* l) {
  __builtin_amdgcn_global_load_lds((const AS1 void*)g, (AS3 void*)l, 16, 0, 0);
}

__device__ __forceinline__ void split1(float v, __hip_bfloat16& h, __hip_bfloat16& l) {
  h = __float2bfloat16(v);
  l = __float2bfloat16(v - __bfloat162float(h));
}

// =================== fast-path builders ===================

// AcatT rows 0..1023 of WbT: WbT[h*64+m][k] = sum_d w_kv[k][h*64+d]*xq[h][m][d]
__global__ __launch_bounds__(256) void k_acat_t(const float* __restrict__ w_kv,
                                                const float* __restrict__ xq,
                                                __hip_bfloat16* __restrict__ wbth,
                                                __hip_bfloat16* __restrict__ wbtl) {
  int hd = blockIdx.x >> 3, kt = blockIdx.x & 7, k0 = kt * 128;
  __shared__ float xqs[64 * 65];
  __shared__ float wks[128 * 65];
  int t = threadIdx.x;
  for (int j = 0; j < 16; ++j) {
    int idx = t + 256 * j; int m = idx >> 6, d = idx & 63;
    xqs[m * 65 + d] = xq[hd * 4096 + idx];
  }
  for (int j = 0; j < 32; ++j) {
    int idx = t + 256 * j; int r = idx >> 6, c = idx & 63;
    wks[r * 65 + c] = w_kv[(size_t)(k0 + r) * 2048 + hd * 64 + c];
  }
  __syncthreads();
  int m = t & 63, kg = t >> 6;
  __hip_bfloat16 hbuf[32], lbuf[32];
  for (int i = 0; i < 32; ++i) {
    int k = kg * 32 + i;
    float s = 0.f;
    #pragma unroll 8
    for (int d = 0; d < 64; ++d) s = fmaf(wks[k * 65 + d], xqs[m * 65 + d], s);
    split1(s, hbuf[i], lbuf[i]);
  }
  size_t o = (size_t)(hd * 64 + m) * 1024 + k0 + kg * 32;
  for (int i = 0; i < 32; i += 8) {
    *(uint4*)&wbth[o + i] = *(uint4*)&hbuf[i];
    *(uint4*)&wbtl[o + i] = *(uint4*)&lbuf[i];
  }
}

// transpose + split a 1024x1024 fp32 block: dst[c][r] = src[r*ld + c]
__global__ __launch_bounds__(256) void k_tsplit(const float* __restrict__ src, int ld,
                                                __hip_bfloat16* __restrict__ dh,
                                                __hip_bfloat16* __restrict__ dl) {
  __shared__ float tile[64 * 65];
  int br = blockIdx.y * 64, bc = blockIdx.x * 64;
  int t = threadIdx.x;
  for (int j = 0; j < 16; ++j) {
    int idx = t + 256 * j; int r = idx >> 6, c = idx & 63;
    tile[r * 65 + c] = src[(size_t)(br + r) * ld + bc + c];
  }
  __syncthreads();
  for (int j = 0; j < 16; ++j) {
    int idx = t + 256 * j; int c = idx >> 6, r = idx & 63;
    float v = tile[r * 65 + c];
    __hip_bfloat16 hv, lv; split1(v, hv, lv);
    size_t o = (size_t)(bc + c) * 1024 + br + r;
    dh[o] = hv; dl[o] = lv;
  }
}

// split contiguous fp32 -> bf16 hi/lo (8 elems/thread)
__global__ void k_split(const float* __restrict__ src, __hip_bfloat16* __restrict__ hi,
                        __hip_bfloat16* __restrict__ lo) {
  size_t base = ((size_t)blockIdx.x * 256 + threadIdx.x) * 8;
  float4 v0 = *(const float4*)&src[base];
  float4 v1 = *(const float4*)&src[base + 4];
  float vv[8] = {v0.x, v0.y, v0.z, v0.w, v1.x, v1.y, v1.z, v1.w};
  __hip_bfloat16 h8[8], l8[8];
  #pragma unroll
  for (int i = 0; i < 8; ++i) split1(vv[i], h8[i], l8[i]);
  *(uint4*)&hi[base] = *(uint4*)h8;
  *(uint4*)&lo[base] = *(uint4*)l8;
}

// =================== fused 3-term 256x256 MFMA NT GEMM =====================
// C[M,N] = (Ah+Al)·(Bh+Bl)^T + bias ≈ AhBh + AhBl + AlBh.
// 512 thr = 8 waves (2M x 4N), per-wave 128x64 out, BK=32, 32 K-tiles.
// LDS: 2 buffers x 64KB {Ah 16K | Al 16K | Bh 16K | Bl 16K}; stage(tt+1) all
// 8 glds16 in P0 of tile tt (~2 phases of latency cover before the tile-end
// own-wave vmcnt(0)). 3 phases/tile, each {ds_read frags ∥ barrier ∥ 32 MFMA}
// with register reuse: P0 ah,bh -> AhBh; P1 bl (ah live) -> AhBl;
// P2 al->ah regs (bh live) -> AlBh.
// T2 swizzle (verified, conflicts=0): element (row, k-octet kq) at byte
//   (row>>1)*128 + ((((row&1)<<2)|kq) ^ ((row>>1)&7))*16 per 16KB region;
// writes keep linear glds dest, inverse permutation on global src address.
// Safety: all ds_reads MFMA-consumed pre-barrier; stage targets the
// opposite-parity buffer (readers retired one barrier earlier); vmcnt(0) at
// tile end counts only own-wave loads; nothing outstanding at endpgm.
__global__ __launch_bounds__(512, 2) void k_mfma8(
    const __hip_bfloat16* __restrict__ Ah, const __hip_bfloat16* __restrict__ Al,
    const __hip_bfloat16* __restrict__ Bh, const __hip_bfloat16* __restrict__ Bl,
    const float* __restrict__ bias, float* __restrict__ C, int ldc) {
  __shared__ __align__(16) char lds[131072];
  const int t = threadIdx.x;
  const int w = t >> 6, lane = t & 63;

  // T1: XCD-aware bijective block swizzle (nwg % 8 == 0 in both uses)
  const int gx = gridDim.x;
  const int nwg = gx * gridDim.y;
  const int bid = blockIdx.y * gx + blockIdx.x;
  const int swzb = (bid & 7) * (nwg >> 3) + (bid >> 3);
  const int n0 = (swzb % gx) * 256;
  const int m0 = (swzb / gx) * 256;

  const int wr = w >> 2, wc = w & 3;        // wave grid 2(M) x 4(N)
  const int fm = lane & 15, kq = lane >> 4; // frag row / k-octet

  // read-side swizzled LDS byte offsets (within a 16KB region)
  int offA[8], offB[4];
  #pragma unroll
  for (int i = 0; i < 8; ++i) {
    int row = wr * 128 + i * 16 + fm;
    offA[i] = (row >> 1) * 128 + ((((row & 1) << 2) | kq) ^ ((row >> 1) & 7)) * 16;
  }
  #pragma unroll
  for (int j = 0; j < 4; ++j) {
    int row = wc * 64 + j * 16 + fm;
    offB[j] = (row >> 1) * 128 + ((((row & 1) << 2) | kq) ^ ((row >> 1) & 7)) * 16;
  }

  // write-side: lane l fills LDS slot l of its 1KB window; the element that
  // belongs there is (row = 2*(l>>3) + (su>>2), octet = su&3), su=(l&7)^(l>>3)
  const int sp = lane >> 3, su = (lane & 7) ^ sp;
  const int srow = 2 * sp + (su >> 2);
  const int scol = (su & 3) * 8;
  const int aO0 = (m0 + w * 16 + srow) * 1024 + scol;
  const int aO1 = aO0 + 128 * 1024;
  const int bO0 = (n0 + w * 16 + srow) * 1024 + scol;
  const int bO1 = bO0 + 128 * 1024;
  const int ldst = w * 1024 + lane * 16;    // LDS byte offset (window w, slot l)

  f32x4 acc[8][4];
  #pragma unroll
  for (int i = 0; i < 8; ++i)
    #pragma unroll
    for (int j = 0; j < 4; ++j) acc[i][j] = (f32x4){0.f, 0.f, 0.f, 0.f};

  // stage all 4 arrays for K-tile ts into buffer buf {Ah|Al|Bh|Bl}
  auto stage = [&](int ts, char* buf) {
    int koff = ts * 32;
    glds16(Ah + aO0 + koff, buf + ldst);
    glds16(Ah + aO1 + koff, buf + 8192 + ldst);
    glds16(Al + aO0 + koff, buf + 16384 + ldst);
    glds16(Al + aO1 + koff, buf + 24576 + ldst);
    glds16(Bh + bO0 + koff, buf + 32768 + ldst);
    glds16(Bh + bO1 + koff, buf + 40960 + ldst);
    glds16(Bl + bO0 + koff, buf + 49152 + ldst);
    glds16(Bl + bO1 + koff, buf + 57344 + ldst);
  };

  // prologue: stage tile 0 into buf0, drain (own-wave), sync
  stage(0, lds);
  asm volatile("s_waitcnt vmcnt(0)" ::: "memory");
  __builtin_amdgcn_s_barrier();
  __builtin_amdgcn_sched_barrier(0);

  #pragma unroll 2
  for (int tt = 0; tt < 32; ++tt) {
    char* rb = &lds[(tt & 1) * 65536];
    char* wb = &lds[((tt + 1) & 1) * 65536];

    // ---- P0: read ah(8)+bh(4) | stage tile tt+1 | MFMA AhBh (32) ----
    short8 ah[8], bh[4], xb[4];
    #pragma unroll
    for (int i = 0; i < 8; ++i) ah[i] = *(const short8*)(rb + offA[i]);
    #pragma unroll
    for (int j = 0; j < 4; ++j) bh[j] = *(const short8*)(rb + 32768 + offB[j]);
    if (tt < 31) stage(tt + 1, wb);
    __builtin_amdgcn_s_barrier();
    __builtin_amdgcn_sched_barrier(0);
    __builtin_amdgcn_s_setprio(1);
    #pragma unroll
    for (int i = 0; i < 8; ++i)
      #pragma unroll
      for (int j = 0; j < 4; ++j)
        acc[i][j] = __builtin_amdgcn_mfma_f32_16x16x32_bf16(ah[i], bh[j], acc[i][j], 0, 0, 0);
    __builtin_amdgcn_s_setprio(0);
    __builtin_amdgcn_s_barrier();
    __builtin_amdgcn_sched_barrier(0);

    // ---- P1: read bl(4), ah reused | MFMA AhBl (32) ----
    #pragma unroll
    for (int j = 0; j < 4; ++j) xb[j] = *(const short8*)(rb + 49152 + offB[j]);
    __builtin_amdgcn_s_barrier();
    __builtin_amdgcn_sched_barrier(0);
    __builtin_amdgcn_s_setprio(1);
    #pragma unroll
    for (int i = 0; i < 8; ++i)
      #pragma unroll
      for (int j = 0; j < 4; ++j)
        acc[i][j] = __builtin_amdgcn_mfma_f32_16x16x32_bf16(ah[i], xb[j], acc[i][j], 0, 0, 0);
    __builtin_amdgcn_s_setprio(0);
    __builtin_amdgcn_s_barrier();
    __builtin_amdgcn_sched_barrier(0);

    // ---- P2: read al(8) into ah regs, bh reused | MFMA AlBh (32) ----
    #pragma unroll
    for (int i = 0; i < 8; ++i) ah[i] = *(const short8*)(rb + 16384 + offA[i]);
    __builtin_amdgcn_s_barrier();
    __builtin_amdgcn_sched_barrier(0);
    __builtin_amdgcn_s_setprio(1);
    #pragma unroll
    for (int i = 0; i < 8; ++i)
      #pragma unroll
      for (int j = 0; j < 4; ++j)
        acc[i][j] = __builtin_amdgcn_mfma_f32_16x16x32_bf16(ah[i], bh[j], acc[i][j], 0, 0, 0);
    __builtin_amdgcn_s_setprio(0);
    // own-wave loads for tile tt+1 (issued in P0) now complete
    asm volatile("s_waitcnt vmcnt(0)" ::: "memory");
    __builtin_amdgcn_s_barrier();
    __builtin_amdgcn_sched_barrier(0);
  }

  // safety drain (nothing should be outstanding — round-4 lesson)
  asm volatile("s_waitcnt vmcnt(0)" ::: "memory");

  // epilogue: C/D map col=lane&15, row=(lane>>4)*4+reg
  const int cm = (lane >> 4) * 4, cn = lane & 15;
  #pragma unroll
  for (int j = 0; j < 4; ++j) {
    int col = n0 + wc * 64 + j * 16 + cn;
    float bbv = bias[col];
    #pragma unroll
    for (int i = 0; i < 8; ++i) {
      int row = m0 + wr * 128 + i * 16 + cm;
      f32x4 v = acc[i][j];
      #pragma unroll
      for (int r = 0; r < 4; ++r)
        C[(size_t)(row + r) * ldc + col] = v[r] + bbv;
    }
  }
}

// =================== fallback builders (round-2) ===================
__global__ __launch_bounds__(256) void k_acat(const float* __restrict__ w_kv,
                                              const float* __restrict__ xq,
                                              float* __restrict__ wbig) {
  int h = blockIdx.x >> 3, kt = blockIdx.x & 7, k0 = kt * 128;
  __shared__ float xqs[64 * 68];
  __shared__ float wks[128 * 68];
  int t = threadIdx.x;
  for (int j = 0; j < 16; ++j) {
    int idx = t + 256 * j; int m = idx >> 6, d = idx & 63;
    xqs[m * 68 + d] = xq[h * 4096 + idx];
  }
  for (int j = 0; j < 32; ++j) {
    int idx = t + 256 * j; int r = idx >> 6, c = idx & 63;
    wks[r * 68 + c] = w_kv[(k0 + r) * 2048 + h * 64 + c];
  }
  __syncthreads();
  int k = t >> 1, half = t & 1;
  float out[32];
  for (int mi = 0; mi < 32; ++mi) {
    int m = half * 32 + mi;
    float s = 0.f;
    #pragma unroll 8
    for (int d = 0; d < 64; ++d) s = fmaf(wks[k * 68 + d], xqs[m * 68 + d], s);
    out[mi] = s;
  }
  float* dst = &wbig[(k0 + k) * 2048 + h * 64 + half * 32];
  for (int mi = 0; mi < 32; mi += 4)
    *(float4*)(dst + mi) = make_float4(out[mi], out[mi + 1], out[mi + 2], out[mi + 3]);
}

__global__ void k_copyv(const float* __restrict__ w_kv, float* __restrict__ wbig) {
  int idx4 = blockIdx.x * 256 + threadIdx.x;
  int k = idx4 >> 8, j4 = idx4 & 255;
  int off = k * 2048 + 1024 + j4 * 4;
  *(float4*)(wbig + off) = *(const float4*)(w_kv + off);
}

__global__ void k_bias1(const float* __restrict__ xq, const float* __restrict__ b_kv,
                        float* __restrict__ bias1) {
  int j = blockIdx.x * 256 + threadIdx.x;
  if (j < 1024) {
    int h = j >> 6, m = j & 63;
    float s = 0.f;
    for (int d = 0; d < 64; ++d) s = fmaf(xq[h * 4096 + m * 64 + d], b_kv[h * 64 + d], s);
    bias1[j] = s;
  } else {
    bias1[j] = b_kv[j];
  }
}

__global__ __launch_bounds__(256) void k_temp(const float* __restrict__ x,
                                              const float* __restrict__ w_temp,
                                              const float* __restrict__ b_temp,
                                              float* __restrict__ T) {
  __shared__ float xs[16 * 1028];
  int t = threadIdx.x;
  int bn0 = blockIdx.x * 16;
  for (int j = 0; j < 16; ++j) {
    int idx4 = t + 256 * j; int row = idx4 >> 8, c4 = (idx4 & 255) * 4;
    *(float4*)&xs[row * 1028 + c4] = *(const float4*)&x[(bn0 + row) * 1024 + c4];
  }
  __syncthreads();
  int tok = t >> 4, j = t & 15;
  float z = b_temp[j];
  for (int k = 0; k < 1024; ++k) z = fmaf(xs[tok * 1028 + k], w_temp[k * 16 + j], z);
  float sp = fmaxf(z, 0.f) + log1pf(expf(-fabsf(z)));
  T[(bn0 + tok) * 16 + j] = 0.5f + sp;
}

__global__ __launch_bounds__(256) void k_gemm(const float* __restrict__ A, int lda,
                                              const float* __restrict__ Bm, int ldb,
                                              const float* __restrict__ bias,
                                              float* __restrict__ C, int ldc, int K) {
  __shared__ float As[8 * 132];
  __shared__ float Bs[8 * 132];
  int t = threadIdx.x;
  int m0 = blockIdx.y * 128, n0 = blockIdx.x * 128;
  int ar = t >> 1, ac = (t & 1) * 4;
  int bk = t >> 5, bc = (t & 31) * 4;
  const float* Ag = A + (size_t)(m0 + ar) * lda + ac;
  const float* Bg = Bm + (size_t)bk * ldb + n0 + bc;
  int tx = t & 15, ty = t >> 4;
  float acc[8][8] = {};
  float4 a4 = *(const float4*)Ag;
  float4 b4 = *(const float4*)Bg;
  for (int kt = 0; kt < K; kt += 8) {
    __syncthreads();
    As[(ac + 0) * 132 + ar] = a4.x;
    As[(ac + 1) * 132 + ar] = a4.y;
    As[(ac + 2) * 132 + ar] = a4.z;
    As[(ac + 3) * 132 + ar] = a4.w;
    *(float4*)&Bs[bk * 132 + bc] = b4;
    __syncthreads();
    if (kt + 8 < K) {
      a4 = *(const float4*)(Ag + kt + 8);
      b4 = *(const float4*)(Bg + (size_t)(kt + 8) * ldb);
    }
    #pragma unroll
    for (int k = 0; k < 8; ++k) {
      float av[8], bv[8];
      *(float4*)&av[0] = *(float4*)&As[k * 132 + ty * 8];
      *(float4*)&av[4] = *(float4*)&As[k * 132 + ty * 8 + 4];
      *(float4*)&bv[0] = *(float4*)&Bs[k * 132 + tx * 4];
      *(float4*)&bv[4] = *(float4*)&Bs[k * 132 + 64 + tx * 4];
      #pragma unroll
      for (int i = 0; i < 8; ++i)
        #pragma unroll
        for (int j = 0; j < 8; ++j) acc[i][j] = fmaf(av[i], bv[j], acc[i][j]);
    }
  }
  float4 bb0 = *(const float4*)&bias[n0 + tx * 4];
  float4 bb1 = *(const float4*)&bias[n0 + 64 + tx * 4];
  #pragma unroll
  for (int i = 0; i < 8; ++i) {
    float* crow = C + (size_t)(m0 + ty * 8 + i) * ldc + n0;
    float4 o0 = make_float4(acc[i][0] + bb0.x, acc[i][1] + bb0.y,
                            acc[i][2] + bb0.z, acc[i][3] + bb0.w);
    float4 o1 = make_float4(acc[i][4] + bb1.x, acc[i][5] + bb1.y,
                            acc[i][6] + bb1.z, acc[i][7] + bb1.w);
    *(float4*)&crow[tx * 4] = o0;
    *(float4*)&crow[64 + tx * 4] = o1;
  }
}

// ------------- stage B: in-place softmax over m + token/norm accumulation ----
__global__ __launch_bounds__(256) void k_smax(float* __restrict__ S, const float* __restrict__ T,
                                              float* __restrict__ token, float* __restrict__ norm) {
  int pair = blockIdx.x >> 3, chunk = blockIdx.x & 7;
  int b = pair >> 4, h = pair & 15;
  __shared__ float sm[128 * 68];
  __shared__ float xv[128 * 68];
  int t = threadIdx.x;
  int m = t >> 2, dg = t & 3;
  float acc[16] = {};
  float nacc = 0.f;
  for (int s = 0; s < 8; ++s) {
    int bn0 = b * 8192 + chunk * 1024 + s * 128;
    for (int jj = 0; jj < 8; ++jj) {
      int idx4 = t + 256 * jj; int row = idx4 >> 4, c4 = (idx4 & 15) * 4;
      int g = (bn0 + row) * 2048 + h * 64 + c4;
      *(float4*)&sm[row * 68 + c4] = *(const float4*)&S[g];
      *(float4*)&xv[row * 68 + c4] = *(const float4*)&S[g + 1024];
    }
    __syncthreads();
    if (t < 128) {
      float tt = T[(bn0 + t) * 16 + h];
      float inv = 1.f / tt;
      float* row = &sm[t * 68];
      float mx = -1e30f;
      for (int mm = 0; mm < 64; ++mm) mx = fmaxf(mx, row[mm]);
      float sum = 0.f;
      for (int mm = 0; mm < 64; ++mm) { float e = expf((row[mm] - mx) * inv); row[mm] = e; sum += e; }
      float sinv = 1.f / sum;
      for (int mm = 0; mm < 64; ++mm) row[mm] *= sinv;
    }
    __syncthreads();
    for (int jj = 0; jj < 8; ++jj) {
      int idx4 = t + 256 * jj; int row = idx4 >> 4, c4 = (idx4 & 15) * 4;
      int g = (bn0 + row) * 2048 + h * 64 + c4;
      *(float4*)&S[g] = *(const float4*)&sm[row * 68 + c4];
    }
    for (int n = 0; n < 128; ++n) {
      float w = sm[n * 68 + m];
      if (dg == 0) nacc += w;
      const float* xr = &xv[n * 68 + dg * 16];
      #pragma unroll
      for (int q = 0; q < 4; ++q) {
        float4 v = *(const float4*)&xr[q * 4];
        acc[q * 4 + 0] = fmaf(w, v.x, acc[q * 4 + 0]);
        acc[q * 4 + 1] = fmaf(w, v.y, acc[q * 4 + 1]);
        acc[q * 4 + 2] = fmaf(w, v.z, acc[q * 4 + 2]);
        acc[q * 4 + 3] = fmaf(w, v.w, acc[q * 4 + 3]);
      }
    }
    __syncthreads();
  }
  int tb = pair * 4096 + m * 64 + dg * 16;
  for (int q = 0; q < 16; ++q) atomicAdd(&token[tb + q], acc[q]);
  if (dg == 0) atomicAdd(&norm[pair * 64 + m], nacc);
}

// ------------- stage C -----------
__global__ __launch_bounds__(256) void k_stagec(const float* __restrict__ token,
                                                const float* __restrict__ norm,
                                                const float* __restrict__ proj,
                                                float* __restrict__ ost) {
  int pair = blockIdx.x; int h = pair & 15;
  __shared__ float st[64 * 68];
  __shared__ float qk[64 * 196];
  int t = threadIdx.x;
  for (int j = 0; j < 16; ++j) {
    int idx = t + 256 * j; int m = idx >> 6, d = idx & 63;
    st[m * 68 + d] = token[pair * 4096 + idx] / (norm[pair * 64 + m] + 1e-5f);
  }
  __syncthreads();
  for (int idx = t; idx < 64 * 192; idx += 256) {
    int m = idx / 192, e = idx % 192;
    float s = 0.f;
    const float* pr = &proj[h * 12288 + e];
    const float* sr = &st[m * 68];
    for (int d = 0; d < 64; ++d) s = fmaf(sr[d], pr[d * 192], s);
    qk[m * 196 + e] = s;
  }
  __syncthreads();
  if (t < 64) {
    const float* q = &qk[t * 196];
    float dots[64];
    float mx = -1e30f;
    for (int d = 0; d < 64; ++d) { dots[d] = q[d] * q[64 + d] * 0.125f; mx = fmaxf(mx, dots[d]); }
    float sum = 0.f;
    for (int d = 0; d < 64; ++d) { dots[d] = expf(dots[d] - mx); sum += dots[d]; }
    float sinv = 1.f / sum;
    for (int d = 0; d < 64; ++d) ost[pair * 4096 + t * 64 + d] = dots[d] * sinv * q[128 + d];
  }
}

// ------------- stage D (fallback: fp32 into S) -----------
__global__ __launch_bounds__(256) void k_staged(float* __restrict__ S, const float* __restrict__ ost) {
  int pair = blockIdx.x >> 6, chunk = blockIdx.x & 63;
  int b = pair >> 4, h = pair & 15;
  __shared__ float ws[128 * 68];
  int t = threadIdx.x;
  int bn0 = b * 8192 + chunk * 128;
  for (int jj = 0; jj < 8; ++jj) {
    int idx4 = t + 256 * jj; int row = idx4 >> 4, c4 = (idx4 & 15) * 4;
    *(float4*)&ws[row * 68 + c4] = *(const float4*)&S[(bn0 + row) * 2048 + h * 64 + c4];
  }
  int d = t & 63, ng = t >> 6;
  float o[64];
  #pragma unroll
  for (int mm = 0; mm < 64; ++mm) o[mm] = ost[pair * 4096 + mm * 64 + d];
  __syncthreads();
  for (int i = 0; i < 32; ++i) {
    int n = ng + 4 * i;
    const float* wr = &ws[n * 68];
    float s = 0.f;
    #pragma unroll
    for (int mm = 0; mm < 64; ++mm) s = fmaf(wr[mm], o[mm], s);
    S[(bn0 + n) * 2048 + 1024 + h * 64 + d] = s;
  }
}

// ------------- stage D (fast: bf16 hi/lo out_x, packed lda=1024) -----------
__global__ __launch_bounds__(256) void k_staged_bf(const float* __restrict__ S,
                                                   const float* __restrict__ ost,
                                                   __hip_bfloat16* __restrict__ oxh,
                                                   __hip_bfloat16* __restrict__ oxl) {
  int pair = blockIdx.x >> 6, chunk = blockIdx.x & 63;
  int b = pair >> 4, hd = pair & 15;
  __shared__ float ws[128 * 68];
  int t = threadIdx.x;
  int bn0 = b * 8192 + chunk * 128;
  for (int jj = 0; jj < 8; ++jj) {
    int idx4 = t + 256 * jj; int row = idx4 >> 4, c4 = (idx4 & 15) * 4;
    *(float4*)&ws[row * 68 + c4] = *(const float4*)&S[(bn0 + row) * 2048 + hd * 64 + c4];
  }
  int d = t & 63, ng = t >> 6;
  float o[64];
  #pragma unroll
  for (int mm = 0; mm < 64; ++mm) o[mm] = ost[pair * 4096 + mm * 64 + d];
  __syncthreads();
  for (int i = 0; i < 32; ++i) {
    int n = ng + 4 * i;
    const float* wr = &ws[n * 68];
    float s = 0.f;
    #pragma unroll
    for (int mm = 0; mm < 64; ++mm) s = fmaf(wr[mm], o[mm], s);
    __hip_bfloat16 hv, lv; split1(s, hv, lv);
    size_t oo = (size_t)(bn0 + n) * 1024 + hd * 64 + d;
    oxh[oo] = hv; oxl[oo] = lv;
  }
}

extern "C" void kernel_launch(void* const* d_in, const int* in_sizes, int n_in,
                              void* d_out, int out_size, void* d_ws, size_t ws_size,
                              hipStream_t stream) {
  const float* x      = (const float*)d_in[0];
  const float* w_kv   = (const float*)d_in[2];
  const float* b_kv   = (const float*)d_in[3];
  const float* w_temp = (const float*)d_in[4];
  const float* b_temp = (const float*)d_in[5];
  const float* xq     = (const float*)d_in[6];
  const float* proj   = (const float*)d_in[7];
  const float* w_out  = (const float*)d_in[8];
  const float* b_out  = (const float*)d_in[9];
  float* out = (float*)d_out;

  float* ws    = (float*)d_ws;
  float* S     = ws;                       // [32768][2048] fp32
  float* T     = S + 67108864;             // [32768][16]
  float* BIAS1 = T + 524288;               // [2048]
  float* TOKEN = BIAS1 + 2048;             // 262144
  float* NORM  = TOKEN + 262144;           // 4096
  float* OST   = NORM + 4096;              // 262144
  float* FEND  = OST + 262144;
  __hip_bfloat16* WbTh = (__hip_bfloat16*)FEND;   // [2048][1024]
  __hip_bfloat16* WbTl = WbTh + 2097152;          // [2048][1024]
  __hip_bfloat16* WoTh = WbTl + 2097152;          // [1024][1024]
  __hip_bfloat16* WoTl = WoTh + 1048576;          // [1024][1024]
  __hip_bfloat16* XH   = WoTl + 1048576;          // [32768][1024] (reused as out_x hi)
  __hip_bfloat16* XL   = XH + 33554432;           // [32768][1024] (reused as out_x lo)
  const size_t need_fast = 419454976ULL;          // bytes

  hipMemsetAsync(TOKEN, 0, (262144 + 4096) * sizeof(float), stream);
  k_bias1<<<8, 256, 0, stream>>>(xq, b_kv, BIAS1);
  k_temp<<<2048, 256, 0, stream>>>(x, w_temp, b_temp, T);

  if (ws_size >= need_fast) {
    // ---- fast path: fused 3-term 256x256 pipelined MFMA GEMMs ----
    k_acat_t<<<128, 256, 0, stream>>>(w_kv, xq, WbTh, WbTl);
    k_tsplit<<<dim3(16, 16), 256, 0, stream>>>(w_kv + 1024, 2048,
                                               WbTh + 1048576, WbTl + 1048576);
    k_tsplit<<<dim3(16, 16), 256, 0, stream>>>(w_out, 1024, WoTh, WoTl);
    k_split<<<16384, 256, 0, stream>>>(x, XH, XL);
    k_mfma8<<<dim3(8, 128), 512, 0, stream>>>(XH, XL, WbTh, WbTl, BIAS1, S, 2048);
    k_smax<<<512, 256, 0, stream>>>(S, T, TOKEN, NORM);
    k_stagec<<<64, 256, 0, stream>>>(TOKEN, NORM, proj, OST);
    k_staged_bf<<<4096, 256, 0, stream>>>(S, OST, XH, XL);
    k_mfma8<<<dim3(4, 128), 512, 0, stream>>>(XH, XL, WoTh, WoTl, b_out, out, 1024);
  } else {
    // ---- fallback: round-2 fp32 vector GEMMs ----
    float* WBIG = (float*)WbTh;            // [1024][2048] fp32 fits in WbTh+WbTl
    k_acat<<<128, 256, 0, stream>>>(w_kv, xq, WBIG);
    k_copyv<<<1024, 256, 0, stream>>>(w_kv, WBIG);
    k_gemm<<<dim3(16, 256), 256, 0, stream>>>(x, 1024, WBIG, 2048, BIAS1, S, 2048, 1024);
    k_smax<<<512, 256, 0, stream>>>(S, T, TOKEN, NORM);
    k_stagec<<<64, 256, 0, stream>>>(TOKEN, NORM, proj, OST);
    k_staged<<<4096, 256, 0, stream>>>(S, OST);
    k_gemm<<<dim3(8, 256), 256, 0, stream>>>(S + 1024, 2048, w_out, 1024, b_out, out, 1024, 1024);
  }
}

// Round 4
// 1416.726 us; speedup vs baseline: 1.0830x; 1.0830x over previous
//
#include <hip/hip_runtime.h>
#include <hip/hip_bf16.h>

// SliceAttention on MI355X — round 7: parity-paired 3-term GEMM.
// Round-5 (412µs, 46% util): depth-3 counted-vmcnt pipeline, no stalls, but
// 36 LDS reads/k and 6 staging passes. Round-6 (479µs, 38%): reg-reuse cut
// reads/fetch (-33%/-31%, confirmed) but depth-1 vmcnt(0) drain cost ~2800
// cyc/tile of burst-stall. This round: virtual tiles v=2k:{Ah,Bh}[k],
// v=2k+1:{Al,Bl}[k] in a 4x32KB rotation (depth-3, vmcnt(8), round-5
// discipline) with ah/bh registers carried across the odd tile for the
// correction terms (24 reads/k, 4 staging passes), and ONE barrier per tile
// so waves desync and DS reads overlap MFMA across waves.

#define NTOK 32768   // B*N
#define HH   1024
#define NHD  16
#define DD   64

typedef short short8 __attribute__((ext_vector_type(8)));
typedef float f32x4 __attribute__((ext_vector_type(4)));

#define AS1 __attribute__((address_space(1)))
#define AS3 __attribute__((address_space(3)))

__device__ __forceinline__ void glds16(const void* g, void* l) {
  __builtin_amdgcn_global_load_lds((const AS1 void*)g, (AS3 void*)l, 16, 0, 0);
}

__device__ __forceinline__ void split1(float v, __hip_bfloat16& h, __hip_bfloat16& l) {
  h = __float2bfloat16(v);
  l = __float2bfloat16(v - __bfloat162float(h));
}

// =================== fast-path builders ===================

// AcatT rows 0..1023 of WbT: WbT[h*64+m][k] = sum_d w_kv[k][h*64+d]*xq[h][m][d]
__global__ __launch_bounds__(256) void k_acat_t(const float* __restrict__ w_kv,
                                                const float* __restrict__ xq,
                                                __hip_bfloat16* __restrict__ wbth,
                                                __hip_bfloat16* __restrict__ wbtl) {
  int hd = blockIdx.x >> 3, kt = blockIdx.x & 7, k0 = kt * 128;
  __shared__ float xqs[64 * 65];
  __shared__ float wks[128 * 65];
  int t = threadIdx.x;
  for (int j = 0; j < 16; ++j) {
    int idx = t + 256 * j; int m = idx >> 6, d = idx & 63;
    xqs[m * 65 + d] = xq[hd * 4096 + idx];
  }
  for (int j = 0; j < 32; ++j) {
    int idx = t + 256 * j; int r = idx >> 6, c = idx & 63;
    wks[r * 65 + c] = w_kv[(size_t)(k0 + r) * 2048 + hd * 64 + c];
  }
  __syncthreads();
  int m = t & 63, kg = t >> 6;
  __hip_bfloat16 hbuf[32], lbuf[32];
  for (int i = 0; i < 32; ++i) {
    int k = kg * 32 + i;
    float s = 0.f;
    #pragma unroll 8
    for (int d = 0; d < 64; ++d) s = fmaf(wks[k * 65 + d], xqs[m * 65 + d], s);
    split1(s, hbuf[i], lbuf[i]);
  }
  size_t o = (size_t)(hd * 64 + m) * 1024 + k0 + kg * 32;
  for (int i = 0; i < 32; i += 8) {
    *(uint4*)&wbth[o + i] = *(uint4*)&hbuf[i];
    *(uint4*)&wbtl[o + i] = *(uint4*)&lbuf[i];
  }
}

// transpose + split a 1024x1024 fp32 block: dst[c][r] = src[r*ld + c]
__global__ __launch_bounds__(256) void k_tsplit(const float* __restrict__ src, int ld,
                                                __hip_bfloat16* __restrict__ dh,
                                                __hip_bfloat16* __restrict__ dl) {
  __shared__ float tile[64 * 65];
  int br = blockIdx.y * 64, bc = blockIdx.x * 64;
  int t = threadIdx.x;
  for (int j = 0; j < 16; ++j) {
    int idx = t + 256 * j; int r = idx >> 6, c = idx & 63;
    tile[r * 65 + c] = src[(size_t)(br + r) * ld + bc + c];
  }
  __syncthreads();
  for (int j = 0; j < 16; ++j) {
    int idx = t + 256 * j; int c = idx >> 6, r = idx & 63;
    float v = tile[r * 65 + c];
    __hip_bfloat16 hv, lv; split1(v, hv, lv);
    size_t o = (size_t)(bc + c) * 1024 + br + r;
    dh[o] = hv; dl[o] = lv;
  }
}

// split contiguous fp32 -> bf16 hi/lo (8 elems/thread)
__global__ void k_split(const float* __restrict__ src, __hip_bfloat16* __restrict__ hi,
                        __hip_bfloat16* __restrict__ lo) {
  size_t base = ((size_t)blockIdx.x * 256 + threadIdx.x) * 8;
  float4 v0 = *(const float4*)&src[base];
  float4 v1 = *(const float4*)&src[base + 4];
  float vv[8] = {v0.x, v0.y, v0.z, v0.w, v1.x, v1.y, v1.z, v1.w};
  __hip_bfloat16 h8[8], l8[8];
  #pragma unroll
  for (int i = 0; i < 8; ++i) split1(vv[i], h8[i], l8[i]);
  *(uint4*)&hi[base] = *(uint4*)h8;
  *(uint4*)&lo[base] = *(uint4*)l8;
}

// =================== parity-paired 3-term 256x256 MFMA NT GEMM =============
// C[M,N] = (Ah+Al)·(Bh+Bl)^T + bias ≈ AhBh + AhBl + AlBh.
// 512 thr = 8 waves (2M x 4N), per-wave 128x64 out, BK=32, 64 virtual tiles:
// v=2k -> {Ah,Bh}[k] (32 MFMA), v=2k+1 -> {Al,Bl}[k] (64 MFMA, ah/bh regs
// carried from v=2k). 4 x 32KB LDS rotation, stage(v+3) each tile (4 glds16),
// vmcnt(8) ONCE per tile (never 0 in-loop), ONE s_barrier per tile.
// T2 swizzle (verified, conflicts=0): element (row, k-octet kq) at byte
//   (row>>1)*128 + ((((row&1)<<2)|kq) ^ ((row>>1)&7))*16 per 16KB region;
// writes keep linear glds dest, inverse permutation on global src address.
// Safety invariants: every ds_read is MFMA-consumed BEFORE the tile-end
// barrier, so stage(v+3)'s DMA into buffer (v-1)&3 after that barrier cannot
// race the reads; vmcnt(8)+barrier => tile v+1 resident for all waves;
// clamped tail re-stages identical bytes (benign); vmcnt(0) before endpgm.
__global__ __launch_bounds__(512, 2) void k_mfma8(
    const __hip_bfloat16* __restrict__ Ah, const __hip_bfloat16* __restrict__ Al,
    const __hip_bfloat16* __restrict__ Bh, const __hip_bfloat16* __restrict__ Bl,
    const float* __restrict__ bias, float* __restrict__ C, int ldc) {
  __shared__ __align__(16) char lds[131072];
  const int t = threadIdx.x;
  const int w = t >> 6, lane = t & 63;

  // T1: XCD-aware bijective block swizzle (nwg % 8 == 0 in both uses)
  const int gx = gridDim.x;
  const int nwg = gx * gridDim.y;
  const int bid = blockIdx.y * gx + blockIdx.x;
  const int swzb = (bid & 7) * (nwg >> 3) + (bid >> 3);
  const int n0 = (swzb % gx) * 256;
  const int m0 = (swzb / gx) * 256;

  const int wr = w >> 2, wc = w & 3;        // wave grid 2(M) x 4(N)
  const int fm = lane & 15, kq = lane >> 4; // frag row / k-octet

  // read-side swizzled LDS byte offsets (within a 16KB region)
  int offA[8], offB[4];
  #pragma unroll
  for (int i = 0; i < 8; ++i) {
    int row = wr * 128 + i * 16 + fm;
    offA[i] = (row >> 1) * 128 + ((((row & 1) << 2) | kq) ^ ((row >> 1) & 7)) * 16;
  }
  #pragma unroll
  for (int j = 0; j < 4; ++j) {
    int row = wc * 64 + j * 16 + fm;
    offB[j] = (row >> 1) * 128 + ((((row & 1) << 2) | kq) ^ ((row >> 1) & 7)) * 16;
  }

  // write-side: lane l fills LDS slot l of its 1KB window; the element that
  // belongs there is (row = 2*(l>>3) + (su>>2), octet = su&3), su=(l&7)^(l>>3)
  const int sp = lane >> 3, su = (lane & 7) ^ sp;
  const int srow = 2 * sp + (su >> 2);
  const int scol = (su & 3) * 8;
  const int aO0 = (m0 + w * 16 + srow) * 1024 + scol;
  const int aO1 = aO0 + 128 * 1024;
  const int bO0 = (n0 + w * 16 + srow) * 1024 + scol;
  const int bO1 = bO0 + 128 * 1024;
  const int ldst = w * 1024 + lane * 16;    // LDS byte offset (window w, slot l)

  f32x4 acc[8][4];
  #pragma unroll
  for (int i = 0; i < 8; ++i)
    #pragma unroll
    for (int j = 0; j < 4; ++j) acc[i][j] = (f32x4){0.f, 0.f, 0.f, 0.f};

  // stage virtual tile ts into buffer ts&3: even ts -> {Ah,Bh}[ts/2],
  // odd ts -> {Al,Bl}[ts/2]. Layout per 32KB buffer: {A 16KB | B 16KB}.
  auto stage = [&](int ts) {
    int koff = (ts >> 1) * 32;
    char* buf = &lds[(ts & 3) * 32768];
    const __hip_bfloat16* As = (ts & 1) ? Al : Ah;
    const __hip_bfloat16* Bs = (ts & 1) ? Bl : Bh;
    glds16(As + aO0 + koff, buf + ldst);
    glds16(As + aO1 + koff, buf + 8192 + ldst);
    glds16(Bs + bO0 + koff, buf + 16384 + ldst);
    glds16(Bs + bO1 + koff, buf + 24576 + ldst);
  };

  // prologue: stage tiles 0..2 (12 loads); vmcnt(8) -> tile 0 resident
  stage(0); stage(1); stage(2);
  asm volatile("s_waitcnt vmcnt(8)" ::: "memory");
  __builtin_amdgcn_s_barrier();
  __builtin_amdgcn_sched_barrier(0);

  short8 ah[8], bh[4], xb[4];
  for (int k = 0; k < 32; ++k) {
    const int v0 = 2 * k, v1 = v0 + 1;
    const char* rb0 = &lds[(v0 & 3) * 32768];
    const char* rb1 = &lds[(v1 & 3) * 32768];

    // ==== even tile v0: {Ah,Bh}[k] -> AhBh ====
    int ts0 = v0 + 3; if (ts0 > 63) ts0 = 63;
    stage(ts0);
    #pragma unroll
    for (int i = 0; i < 8; ++i) ah[i] = *(const short8*)(rb0 + offA[i]);
    #pragma unroll
    for (int j = 0; j < 4; ++j) bh[j] = *(const short8*)(rb0 + 16384 + offB[j]);
    __builtin_amdgcn_s_setprio(1);
    #pragma unroll
    for (int i = 0; i < 8; ++i)
      #pragma unroll
      for (int j = 0; j < 4; ++j)
        acc[i][j] = __builtin_amdgcn_mfma_f32_16x16x32_bf16(ah[i], bh[j], acc[i][j], 0, 0, 0);
    __builtin_amdgcn_s_setprio(0);
    asm volatile("s_waitcnt vmcnt(8)" ::: "memory");  // tile v0+1 resident
    __builtin_amdgcn_s_barrier();
    __builtin_amdgcn_sched_barrier(0);

    // ==== odd tile v1: {Al,Bl}[k] -> AhBl (ah regs) + AlBh (bh regs) ====
    int ts1 = v1 + 3; if (ts1 > 63) ts1 = 63;
    stage(ts1);
    #pragma unroll
    for (int j = 0; j < 4; ++j) xb[j] = *(const short8*)(rb1 + 16384 + offB[j]);
    __builtin_amdgcn_s_setprio(1);
    #pragma unroll
    for (int i = 0; i < 8; ++i)
      #pragma unroll
      for (int j = 0; j < 4; ++j)
        acc[i][j] = __builtin_amdgcn_mfma_f32_16x16x32_bf16(ah[i], xb[j], acc[i][j], 0, 0, 0);
    __builtin_amdgcn_s_setprio(0);
    #pragma unroll
    for (int i = 0; i < 8; ++i) ah[i] = *(const short8*)(rb1 + offA[i]);  // Al
    __builtin_amdgcn_s_setprio(1);
    #pragma unroll
    for (int i = 0; i < 8; ++i)
      #pragma unroll
      for (int j = 0; j < 4; ++j)
        acc[i][j] = __builtin_amdgcn_mfma_f32_16x16x32_bf16(ah[i], bh[j], acc[i][j], 0, 0, 0);
    __builtin_amdgcn_s_setprio(0);
    asm volatile("s_waitcnt vmcnt(8)" ::: "memory");  // tile v1+1 resident
    __builtin_amdgcn_s_barrier();
    __builtin_amdgcn_sched_barrier(0);
  }

  // drain all outstanding LDS-DMA before endpgm (round-4 lesson)
  asm volatile("s_waitcnt vmcnt(0)" ::: "memory");
  __builtin_amdgcn_sched_barrier(0);

  // epilogue: C/D map col=lane&15, row=(lane>>4)*4+reg
  const int cm = (lane >> 4) * 4, cn = lane & 15;
  #pragma unroll
  for (int j = 0; j < 4; ++j) {
    int col = n0 + wc * 64 + j * 16 + cn;
    float bbv = bias[col];
    #pragma unroll
    for (int i = 0; i < 8; ++i) {
      int row = m0 + wr * 128 + i * 16 + cm;
      f32x4 v = acc[i][j];
      #pragma unroll
      for (int r = 0; r < 4; ++r)
        C[(size_t)(row + r) * ldc + col] = v[r] + bbv;
    }
  }
}

// =================== fallback builders (round-2) ===================
__global__ __launch_bounds__(256) void k_acat(const float* __restrict__ w_kv,
                                              const float* __restrict__ xq,
                                              float* __restrict__ wbig) {
  int h = blockIdx.x >> 3, kt = blockIdx.x & 7, k0 = kt * 128;
  __shared__ float xqs[64 * 68];
  __shared__ float wks[128 * 68];
  int t = threadIdx.x;
  for (int j = 0; j < 16; ++j) {
    int idx = t + 256 * j; int m = idx >> 6, d = idx & 63;
    xqs[m * 68 + d] = xq[h * 4096 + idx];
  }
  for (int j = 0; j < 32; ++j) {
    int idx = t + 256 * j; int r = idx >> 6, c = idx & 63;
    wks[r * 68 + c] = w_kv[(k0 + r) * 2048 + h * 64 + c];
  }
  __syncthreads();
  int k = t >> 1, half = t & 1;
  float out[32];
  for (int mi = 0; mi < 32; ++mi) {
    int m = half * 32 + mi;
    float s = 0.f;
    #pragma unroll 8
    for (int d = 0; d < 64; ++d) s = fmaf(wks[k * 68 + d], xqs[m * 68 + d], s);
    out[mi] = s;
  }
  float* dst = &wbig[(k0 + k) * 2048 + h * 64 + half * 32];
  for (int mi = 0; mi < 32; mi += 4)
    *(float4*)(dst + mi) = make_float4(out[mi], out[mi + 1], out[mi + 2], out[mi + 3]);
}

__global__ void k_copyv(const float* __restrict__ w_kv, float* __restrict__ wbig) {
  int idx4 = blockIdx.x * 256 + threadIdx.x;
  int k = idx4 >> 8, j4 = idx4 & 255;
  int off = k * 2048 + 1024 + j4 * 4;
  *(float4*)(wbig + off) = *(const float4*)(w_kv + off);
}

__global__ void k_bias1(const float* __restrict__ xq, const float* __restrict__ b_kv,
                        float* __restrict__ bias1) {
  int j = blockIdx.x * 256 + threadIdx.x;
  if (j < 1024) {
    int h = j >> 6, m = j & 63;
    float s = 0.f;
    for (int d = 0; d < 64; ++d) s = fmaf(xq[h * 4096 + m * 64 + d], b_kv[h * 64 + d], s);
    bias1[j] = s;
  } else {
    bias1[j] = b_kv[j];
  }
}

__global__ __launch_bounds__(256) void k_temp(const float* __restrict__ x,
                                              const float* __restrict__ w_temp,
                                              const float* __restrict__ b_temp,
                                              float* __restrict__ T) {
  __shared__ float xs[16 * 1028];
  int t = threadIdx.x;
  int bn0 = blockIdx.x * 16;
  for (int j = 0; j < 16; ++j) {
    int idx4 = t + 256 * j; int row = idx4 >> 8, c4 = (idx4 & 255) * 4;
    *(float4*)&xs[row * 1028 + c4] = *(const float4*)&x[(bn0 + row) * 1024 + c4];
  }
  __syncthreads();
  int tok = t >> 4, j = t & 15;
  float z = b_temp[j];
  for (int k = 0; k < 1024; ++k) z = fmaf(xs[tok * 1028 + k], w_temp[k * 16 + j], z);
  float sp = fmaxf(z, 0.f) + log1pf(expf(-fabsf(z)));
  T[(bn0 + tok) * 16 + j] = 0.5f + sp;
}

__global__ __launch_bounds__(256) void k_gemm(const float* __restrict__ A, int lda,
                                              const float* __restrict__ Bm, int ldb,
                                              const float* __restrict__ bias,
                                              float* __restrict__ C, int ldc, int K) {
  __shared__ float As[8 * 132];
  __shared__ float Bs[8 * 132];
  int t = threadIdx.x;
  int m0 = blockIdx.y * 128, n0 = blockIdx.x * 128;
  int ar = t >> 1, ac = (t & 1) * 4;
  int bk = t >> 5, bc = (t & 31) * 4;
  const float* Ag = A + (size_t)(m0 + ar) * lda + ac;
  const float* Bg = Bm + (size_t)bk * ldb + n0 + bc;
  int tx = t & 15, ty = t >> 4;
  float acc[8][8] = {};
  float4 a4 = *(const float4*)Ag;
  float4 b4 = *(const float4*)Bg;
  for (int kt = 0; kt < K; kt += 8) {
    __syncthreads();
    As[(ac + 0) * 132 + ar] = a4.x;
    As[(ac + 1) * 132 + ar] = a4.y;
    As[(ac + 2) * 132 + ar] = a4.z;
    As[(ac + 3) * 132 + ar] = a4.w;
    *(float4*)&Bs[bk * 132 + bc] = b4;
    __syncthreads();
    if (kt + 8 < K) {
      a4 = *(const float4*)(Ag + kt + 8);
      b4 = *(const float4*)(Bg + (size_t)(kt + 8) * ldb);
    }
    #pragma unroll
    for (int k = 0; k < 8; ++k) {
      float av[8], bv[8];
      *(float4*)&av[0] = *(float4*)&As[k * 132 + ty * 8];
      *(float4*)&av[4] = *(float4*)&As[k * 132 + ty * 8 + 4];
      *(float4*)&bv[0] = *(float4*)&Bs[k * 132 + tx * 4];
      *(float4*)&bv[4] = *(float4*)&Bs[k * 132 + 64 + tx * 4];
      #pragma unroll
      for (int i = 0; i < 8; ++i)
        #pragma unroll
        for (int j = 0; j < 8; ++j) acc[i][j] = fmaf(av[i], bv[j], acc[i][j]);
    }
  }
  float4 bb0 = *(const float4*)&bias[n0 + tx * 4];
  float4 bb1 = *(const float4*)&bias[n0 + 64 + tx * 4];
  #pragma unroll
  for (int i = 0; i < 8; ++i) {
    float* crow = C + (size_t)(m0 + ty * 8 + i) * ldc + n0;
    float4 o0 = make_float4(acc[i][0] + bb0.x, acc[i][1] + bb0.y,
                            acc[i][2] + bb0.z, acc[i][3] + bb0.w);
    float4 o1 = make_float4(acc[i][4] + bb1.x, acc[i][5] + bb1.y,
                            acc[i][6] + bb1.z, acc[i][7] + bb1.w);
    *(float4*)&crow[tx * 4] = o0;
    *(float4*)&crow[64 + tx * 4] = o1;
  }
}

// ------------- stage B: in-place softmax over m + token/norm accumulation ----
__global__ __launch_bounds__(256) void k_smax(float* __restrict__ S, const float* __restrict__ T,
                                              float* __restrict__ token, float* __restrict__ norm) {
  int pair = blockIdx.x >> 3, chunk = blockIdx.x & 7;
  int b = pair >> 4, h = pair & 15;
  __shared__ float sm[128 * 68];
  __shared__ float xv[128 * 68];
  int t = threadIdx.x;
  int m = t >> 2, dg = t & 3;
  float acc[16] = {};
  float nacc = 0.f;
  for (int s = 0; s < 8; ++s) {
    int bn0 = b * 8192 + chunk * 1024 + s * 128;
    for (int jj = 0; jj < 8; ++jj) {
      int idx4 = t + 256 * jj; int row = idx4 >> 4, c4 = (idx4 & 15) * 4;
      int g = (bn0 + row) * 2048 + h * 64 + c4;
      *(float4*)&sm[row * 68 + c4] = *(const float4*)&S[g];
      *(float4*)&xv[row * 68 + c4] = *(const float4*)&S[g + 1024];
    }
    __syncthreads();
    if (t < 128) {
      float tt = T[(bn0 + t) * 16 + h];
      float inv = 1.f / tt;
      float* row = &sm[t * 68];
      float mx = -1e30f;
      for (int mm = 0; mm < 64; ++mm) mx = fmaxf(mx, row[mm]);
      float sum = 0.f;
      for (int mm = 0; mm < 64; ++mm) { float e = expf((row[mm] - mx) * inv); row[mm] = e; sum += e; }
      float sinv = 1.f / sum;
      for (int mm = 0; mm < 64; ++mm) row[mm] *= sinv;
    }
    __syncthreads();
    for (int jj = 0; jj < 8; ++jj) {
      int idx4 = t + 256 * jj; int row = idx4 >> 4, c4 = (idx4 & 15) * 4;
      int g = (bn0 + row) * 2048 + h * 64 + c4;
      *(float4*)&S[g] = *(const float4*)&sm[row * 68 + c4];
    }
    for (int n = 0; n < 128; ++n) {
      float w = sm[n * 68 + m];
      if (dg == 0) nacc += w;
      const float* xr = &xv[n * 68 + dg * 16];
      #pragma unroll
      for (int q = 0; q < 4; ++q) {
        float4 v = *(const float4*)&xr[q * 4];
        acc[q * 4 + 0] = fmaf(w, v.x, acc[q * 4 + 0]);
        acc[q * 4 + 1] = fmaf(w, v.y, acc[q * 4 + 1]);
        acc[q * 4 + 2] = fmaf(w, v.z, acc[q * 4 + 2]);
        acc[q * 4 + 3] = fmaf(w, v.w, acc[q * 4 + 3]);
      }
    }
    __syncthreads();
  }
  int tb = pair * 4096 + m * 64 + dg * 16;
  for (int q = 0; q < 16; ++q) atomicAdd(&token[tb + q], acc[q]);
  if (dg == 0) atomicAdd(&norm[pair * 64 + m], nacc);
}

// ------------- stage C -----------
__global__ __launch_bounds__(256) void k_stagec(const float* __restrict__ token,
                                                const float* __restrict__ norm,
                                                const float* __restrict__ proj,
                                                float* __restrict__ ost) {
  int pair = blockIdx.x; int h = pair & 15;
  __shared__ float st[64 * 68];
  __shared__ float qk[64 * 196];
  int t = threadIdx.x;
  for (int j = 0; j < 16; ++j) {
    int idx = t + 256 * j; int m = idx >> 6, d = idx & 63;
    st[m * 68 + d] = token[pair * 4096 + idx] / (norm[pair * 64 + m] + 1e-5f);
  }
  __syncthreads();
  for (int idx = t; idx < 64 * 192; idx += 256) {
    int m = idx / 192, e = idx % 192;
    float s = 0.f;
    const float* pr = &proj[h * 12288 + e];
    const float* sr = &st[m * 68];
    for (int d = 0; d < 64; ++d) s = fmaf(sr[d], pr[d * 192], s);
    qk[m * 196 + e] = s;
  }
  __syncthreads();
  if (t < 64) {
    const float* q = &qk[t * 196];
    float dots[64];
    float mx = -1e30f;
    for (int d = 0; d < 64; ++d) { dots[d] = q[d] * q[64 + d] * 0.125f; mx = fmaxf(mx, dots[d]); }
    float sum = 0.f;
    for (int d = 0; d < 64; ++d) { dots[d] = expf(dots[d] - mx); sum += dots[d]; }
    float sinv = 1.f / sum;
    for (int d = 0; d < 64; ++d) ost[pair * 4096 + t * 64 + d] = dots[d] * sinv * q[128 + d];
  }
}

// ------------- stage D (fallback: fp32 into S) -----------
__global__ __launch_bounds__(256) void k_staged(float* __restrict__ S, const float* __restrict__ ost) {
  int pair = blockIdx.x >> 6, chunk = blockIdx.x & 63;
  int b = pair >> 4, h = pair & 15;
  __shared__ float ws[128 * 68];
  int t = threadIdx.x;
  int bn0 = b * 8192 + chunk * 128;
  for (int jj = 0; jj < 8; ++jj) {
    int idx4 = t + 256 * jj; int row = idx4 >> 4, c4 = (idx4 & 15) * 4;
    *(float4*)&ws[row * 68 + c4] = *(const float4*)&S[(bn0 + row) * 2048 + h * 64 + c4];
  }
  int d = t & 63, ng = t >> 6;
  float o[64];
  #pragma unroll
  for (int mm = 0; mm < 64; ++mm) o[mm] = ost[pair * 4096 + mm * 64 + d];
  __syncthreads();
  for (int i = 0; i < 32; ++i) {
    int n = ng + 4 * i;
    const float* wr = &ws[n * 68];
    float s = 0.f;
    #pragma unroll
    for (int mm = 0; mm < 64; ++mm) s = fmaf(wr[mm], o[mm], s);
    S[(bn0 + n) * 2048 + 1024 + h * 64 + d] = s;
  }
}

// ------------- stage D (fast: bf16 hi/lo out_x, packed lda=1024) -----------
__global__ __launch_bounds__(256) void k_staged_bf(const float* __restrict__ S,
                                                   const float* __restrict__ ost,
                                                   __hip_bfloat16* __restrict__ oxh,
                                                   __hip_bfloat16* __restrict__ oxl) {
  int pair = blockIdx.x >> 6, chunk = blockIdx.x & 63;
  int b = pair >> 4, hd = pair & 15;
  __shared__ float ws[128 * 68];
  int t = threadIdx.x;
  int bn0 = b * 8192 + chunk * 128;
  for (int jj = 0; jj < 8; ++jj) {
    int idx4 = t + 256 * jj; int row = idx4 >> 4, c4 = (idx4 & 15) * 4;
    *(float4*)&ws[row * 68 + c4] = *(const float4*)&S[(bn0 + row) * 2048 + hd * 64 + c4];
  }
  int d = t & 63, ng = t >> 6;
  float o[64];
  #pragma unroll
  for (int mm = 0; mm < 64; ++mm) o[mm] = ost[pair * 4096 + mm * 64 + d];
  __syncthreads();
  for (int i = 0; i < 32; ++i) {
    int n = ng + 4 * i;
    const float* wr = &ws[n * 68];
    float s = 0.f;
    #pragma unroll
    for (int mm = 0; mm < 64; ++mm) s = fmaf(wr[mm], o[mm], s);
    __hip_bfloat16 hv, lv; split1(s, hv, lv);
    size_t oo = (size_t)(bn0 + n) * 1024 + hd * 64 + d;
    oxh[oo] = hv; oxl[oo] = lv;
  }
}

extern "C" void kernel_launch(void* const* d_in, const int* in_sizes, int n_in,
                              void* d_out, int out_size, void* d_ws, size_t ws_size,
                              hipStream_t stream) {
  const float* x      = (const float*)d_in[0];
  const float* w_kv   = (const float*)d_in[2];
  const float* b_kv   = (const float*)d_in[3];
  const float* w_temp = (const float*)d_in[4];
  const float* b_temp = (const float*)d_in[5];
  const float* xq     = (const float*)d_in[6];
  const float* proj   = (const float*)d_in[7];
  const float* w_out  = (const float*)d_in[8];
  const float* b_out  = (const float*)d_in[9];
  float* out = (float*)d_out;

  float* ws    = (float*)d_ws;
  float* S     = ws;                       // [32768][2048] fp32
  float* T     = S + 67108864;             // [32768][16]
  float* BIAS1 = T + 524288;               // [2048]
  float* TOKEN = BIAS1 + 2048;             // 262144
  float* NORM  = TOKEN + 262144;           // 4096
  float* OST   = NORM + 4096;              // 262144
  float* FEND  = OST + 262144;
  __hip_bfloat16* WbTh = (__hip_bfloat16*)FEND;   // [2048][1024]
  __hip_bfloat16* WbTl = WbTh + 2097152;          // [2048][1024]
  __hip_bfloat16* WoTh = WbTl + 2097152;          // [1024][1024]
  __hip_bfloat16* WoTl = WoTh + 1048576;          // [1024][1024]
  __hip_bfloat16* XH   = WoTl + 1048576;          // [32768][1024] (reused as out_x hi)
  __hip_bfloat16* XL   = XH + 33554432;           // [32768][1024] (reused as out_x lo)
  const size_t need_fast = 419454976ULL;          // bytes

  hipMemsetAsync(TOKEN, 0, (262144 + 4096) * sizeof(float), stream);
  k_bias1<<<8, 256, 0, stream>>>(xq, b_kv, BIAS1);
  k_temp<<<2048, 256, 0, stream>>>(x, w_temp, b_temp, T);

  if (ws_size >= need_fast) {
    // ---- fast path: parity-paired 3-term 256x256 pipelined MFMA GEMMs ----
    k_acat_t<<<128, 256, 0, stream>>>(w_kv, xq, WbTh, WbTl);
    k_tsplit<<<dim3(16, 16), 256, 0, stream>>>(w_kv + 1024, 2048,
                                               WbTh + 1048576, WbTl + 1048576);
    k_tsplit<<<dim3(16, 16), 256, 0, stream>>>(w_out, 1024, WoTh, WoTl);
    k_split<<<16384, 256, 0, stream>>>(x, XH, XL);
    k_mfma8<<<dim3(8, 128), 512, 0, stream>>>(XH, XL, WbTh, WbTl, BIAS1, S, 2048);
    k_smax<<<512, 256, 0, stream>>>(S, T, TOKEN, NORM);
    k_stagec<<<64, 256, 0, stream>>>(TOKEN, NORM, proj, OST);
    k_staged_bf<<<4096, 256, 0, stream>>>(S, OST, XH, XL);
    k_mfma8<<<dim3(4, 128), 512, 0, stream>>>(XH, XL, WoTh, WoTl, b_out, out, 1024);
  } else {
    // ---- fallback: round-2 fp32 vector GEMMs ----
    float* WBIG = (float*)WbTh;            // [1024][2048] fp32 fits in WbTh+WbTl
    k_acat<<<128, 256, 0, stream>>>(w_kv, xq, WBIG);
    k_copyv<<<1024, 256, 0, stream>>>(w_kv, WBIG);
    k_gemm<<<dim3(16, 256), 256, 0, stream>>>(x, 1024, WBIG, 2048, BIAS1, S, 2048, 1024);
    k_smax<<<512, 256, 0, stream>>>(S, T, TOKEN, NORM);
    k_stagec<<<64, 256, 0, stream>>>(TOKEN, NORM, proj, OST);
    k_staged<<<4096, 256, 0, stream>>>(S, OST);
    k_gemm<<<dim3(8, 256), 256, 0, stream>>>(S + 1024, 2048, w_out, 1024, b_out, out, 1024, 1024);
  }
}